// Round 1
// baseline (1003.340 us; speedup 1.0000x reference)
//
#include <hip/hip_runtime.h>
#include <math.h>

#define H 16
#define D 1024
#define DK 64
#define B 16
#define N 4096
#define SCALE_INV 0.125f

// ws layout (floats):
//   qk     [H][D]      16384
//   scores [B][H][N]   1048576  (in-place softmax -> A)
//   xa     [B][H][D]   262144
//   pooled [B][D]      16384
// total ~5.4 MB

// ---------- qk[h][d] = (1/8) * sum_dk query[h*64+dk] * Wk[(h*64+dk)*D + d] ----------
__global__ __launch_bounds__(256) void qk_kernel(const float* __restrict__ query,
                                                 const float* __restrict__ Wk,
                                                 float* __restrict__ qk) {
    int t = blockIdx.x * 256 + threadIdx.x;   // 0..16383
    int h = t >> 10;
    int d = t & (D - 1);
    float acc = 0.f;
#pragma unroll 8
    for (int dk = 0; dk < DK; ++dk)
        acc += query[h * DK + dk] * Wk[(size_t)(h * DK + dk) * D + d];
    qk[t] = acc * SCALE_INV;
}

// ---------- zero xa ----------
__global__ __launch_bounds__(256) void zero_kernel(float* __restrict__ p, int n4) {
    int t = blockIdx.x * 256 + threadIdx.x;
    if (t < n4) ((float4*)p)[t] = make_float4(0.f, 0.f, 0.f, 0.f);
}

// ---------- scores[b][h][n] = x_row . qk[h] ----------
// block = 256 threads = 16 rows x 16 heads
__global__ __launch_bounds__(256) void scores_kernel(const float* __restrict__ x,
                                                     const float* __restrict__ qk,
                                                     float* __restrict__ scores) {
    int row = blockIdx.x * 16 + (threadIdx.x >> 4);  // global row in [0, B*N)
    int h = threadIdx.x & 15;
    const float4* x4 = (const float4*)(x + (size_t)row * D);
    const float4* q4 = (const float4*)(qk + (size_t)h * D);
    float acc0 = 0.f, acc1 = 0.f;
    for (int i = 0; i < D / 4; i += 2) {
        float4 xv0 = x4[i],     qv0 = q4[i];
        float4 xv1 = x4[i + 1], qv1 = q4[i + 1];
        acc0 += xv0.x * qv0.x + xv0.y * qv0.y + xv0.z * qv0.z + xv0.w * qv0.w;
        acc1 += xv1.x * qv1.x + xv1.y * qv1.y + xv1.z * qv1.z + xv1.w * qv1.w;
    }
    int b = row >> 12;          // N = 4096 = 2^12
    int n = row & (N - 1);
    scores[((size_t)(b * H + h) << 12) + n] = acc0 + acc1;
}

// ---------- softmax over n for each (b,h); one block per (b,h) ----------
__global__ __launch_bounds__(256) void softmax_kernel(float* __restrict__ s) {
    float* p = s + (size_t)blockIdx.x * N;
    int t = threadIdx.x;
    __shared__ float redm[4];
    __shared__ float reds[4];

    float v[16];
    float m = -1e30f;
#pragma unroll
    for (int i = 0; i < 16; ++i) {
        v[i] = p[t + 256 * i];
        m = fmaxf(m, v[i]);
    }
#pragma unroll
    for (int off = 32; off > 0; off >>= 1)
        m = fmaxf(m, __shfl_xor(m, off, 64));
    if ((t & 63) == 0) redm[t >> 6] = m;
    __syncthreads();
    m = fmaxf(fmaxf(redm[0], redm[1]), fmaxf(redm[2], redm[3]));

    float sum = 0.f;
#pragma unroll
    for (int i = 0; i < 16; ++i) {
        v[i] = __expf(v[i] - m);
        sum += v[i];
    }
#pragma unroll
    for (int off = 32; off > 0; off >>= 1)
        sum += __shfl_xor(sum, off, 64);
    if ((t & 63) == 0) reds[t >> 6] = sum;
    __syncthreads();
    sum = reds[0] + reds[1] + reds[2] + reds[3];

    float inv = 1.f / sum;
#pragma unroll
    for (int i = 0; i < 16; ++i) p[t + 256 * i] = v[i] * inv;
}

// ---------- xa[b][h][d] += sum_{n in chunk} A[b][h][n] * x[b][n][d] ----------
// grid = (32 chunks of 128 rows, 16 batches); block = 256 threads, thread t owns d = 4t..4t+3
#define CHUNK 128
__global__ __launch_bounds__(256) void wsum_kernel(const float* __restrict__ x,
                                                   const float* __restrict__ A,
                                                   float* __restrict__ xa) {
    __shared__ float w[H][CHUNK];
    int c = blockIdx.x;
    int b = blockIdx.y;
    int n0 = c * CHUNK;
    int t = threadIdx.x;

    for (int i = t; i < H * CHUNK; i += 256) {
        int h = i / CHUNK;
        int j = i % CHUNK;
        w[h][j] = A[((size_t)(b * H + h) << 12) + n0 + j];
    }
    __syncthreads();

    float4 acc[H];
#pragma unroll
    for (int h = 0; h < H; ++h) acc[h] = make_float4(0.f, 0.f, 0.f, 0.f);

    const float4* x4 = (const float4*)(x + (size_t)(b * N + n0) * D);
    for (int r = 0; r < CHUNK; ++r) {
        float4 xv = x4[(size_t)r * (D / 4) + t];
#pragma unroll
        for (int h = 0; h < H; ++h) {
            float wh = w[h][r];
            acc[h].x += wh * xv.x;
            acc[h].y += wh * xv.y;
            acc[h].z += wh * xv.z;
            acc[h].w += wh * xv.w;
        }
    }

    float* xab = xa + (size_t)b * H * D;
#pragma unroll
    for (int h = 0; h < H; ++h) {
        float* dst = xab + h * D + 4 * t;
        atomicAdd(dst + 0, acc[h].x);
        atomicAdd(dst + 1, acc[h].y);
        atomicAdd(dst + 2, acc[h].z);
        atomicAdd(dst + 3, acc[h].w);
    }
}

// ---------- wave-per-output 1024-dot ----------
__device__ __forceinline__ float wave_dot1024(const float* __restrict__ a,
                                              const float* __restrict__ b) {
    const float4* a4 = (const float4*)a;
    const float4* b4 = (const float4*)b;
    int lane = threadIdx.x & 63;
    float acc = 0.f;
#pragma unroll
    for (int i = 0; i < 4; ++i) {
        float4 av = a4[lane + 64 * i];
        float4 bv = b4[lane + 64 * i];
        acc += av.x * bv.x + av.y * bv.y + av.z * bv.z + av.w * bv.w;
    }
#pragma unroll
    for (int off = 32; off > 0; off >>= 1)
        acc += __shfl_xor(acc, off, 64);
    return acc;
}

// ---------- pooled[b][j] = xa[b][j>>6][:] . Wv[j][:] ----------
__global__ __launch_bounds__(256) void pooled_kernel(const float* __restrict__ xa,
                                                     const float* __restrict__ Wv,
                                                     float* __restrict__ pooled) {
    int o = blockIdx.x * 4 + (threadIdx.x >> 6);  // 0..16383
    int b = o >> 10;
    int j = o & (D - 1);
    int h = j >> 6;
    float v = wave_dot1024(xa + (size_t)(b * H + h) * D, Wv + (size_t)j * D);
    if ((threadIdx.x & 63) == 0) pooled[o] = v;
}

// ---------- out[b][j] = pooled[b][:] . Wout[j][:] + bout[j] ----------
__global__ __launch_bounds__(256) void out_kernel(const float* __restrict__ pooled,
                                                  const float* __restrict__ Wout,
                                                  const float* __restrict__ bout,
                                                  float* __restrict__ out) {
    int o = blockIdx.x * 4 + (threadIdx.x >> 6);  // 0..16383
    int b = o >> 10;
    int j = o & (D - 1);
    float v = wave_dot1024(pooled + (size_t)b * D, Wout + (size_t)j * D);
    if ((threadIdx.x & 63) == 0) out[o] = v + bout[j];
}

extern "C" void kernel_launch(void* const* d_in, const int* in_sizes, int n_in,
                              void* d_out, int out_size, void* d_ws, size_t ws_size,
                              hipStream_t stream) {
    const float* x     = (const float*)d_in[0];
    const float* Wk    = (const float*)d_in[1];
    const float* Wv    = (const float*)d_in[2];
    const float* query = (const float*)d_in[3];
    const float* Wout  = (const float*)d_in[4];
    const float* bout  = (const float*)d_in[5];
    float* out = (float*)d_out;

    float* qk     = (float*)d_ws;                    // 16384
    float* scores = qk + H * D;                      // 1048576
    float* xa     = scores + (size_t)B * H * N;      // 262144
    float* pooled = xa + (size_t)B * H * D;          // 16384

    // qk precompute + zero xa
    qk_kernel<<<64, 256, 0, stream>>>(query, Wk, qk);
    zero_kernel<<<(B * H * D / 4 + 255) / 256, 256, 0, stream>>>(xa, B * H * D / 4);

    // scores: one pass over x
    scores_kernel<<<(B * N) / 16, 256, 0, stream>>>(x, qk, scores);

    // softmax per (b,h)
    softmax_kernel<<<B * H, 256, 0, stream>>>(scores);

    // weighted sum: second pass over x
    wsum_kernel<<<dim3(N / CHUNK, B), 256, 0, stream>>>(x, scores, xa);

    // small tail GEMVs
    pooled_kernel<<<(B * D) / 4, 256, 0, stream>>>(xa, Wv, pooled);
    out_kernel<<<(B * D) / 4, 256, 0, stream>>>(pooled, Wout, bout, out);
}

// Round 2
// 560.066 us; speedup vs baseline: 1.7915x; 1.7915x over previous
//
#include <hip/hip_runtime.h>
#include <math.h>

#define H 16
#define D 1024
#define DK 64
#define B 16
#define N 4096
#define SCALE_INV 0.125f

// ws layout (floats):
//   qk     [H][D]      16384
//   scores [B][H][N]   1048576  (in-place softmax -> A)
//   xa     [B][H][D]   262144
//   pooled [B][D]      16384

// ---------- qk[h][d] = (1/8) * sum_dk query[h*64+dk] * Wk[(h*64+dk)*D + d] ----------
__global__ __launch_bounds__(256) void qk_kernel(const float* __restrict__ query,
                                                 const float* __restrict__ Wk,
                                                 float* __restrict__ qk) {
    int t = blockIdx.x * 256 + threadIdx.x;   // 0..16383
    int h = t >> 10;
    int d = t & (D - 1);
    float acc = 0.f;
#pragma unroll 8
    for (int dk = 0; dk < DK; ++dk)
        acc += query[h * DK + dk] * Wk[(size_t)(h * DK + dk) * D + d];
    qk[t] = acc * SCALE_INV;
}

// ---------- zero xa ----------
__global__ __launch_bounds__(256) void zero_kernel(float* __restrict__ p, int n4) {
    int t = blockIdx.x * 256 + threadIdx.x;
    if (t < n4) ((float4*)p)[t] = make_float4(0.f, 0.f, 0.f, 0.f);
}

// ---------- scores[b][h][n] = x_row . qk[h] ----------
// One wave handles 4 consecutive rows (all 16 heads). qk staged in LDS (64 KB).
// Block = 256 threads = 4 waves = 16 rows. Grid = 65536/16 = 4096 blocks.
__global__ __launch_bounds__(256) void scores_kernel(const float* __restrict__ x,
                                                     const float* __restrict__ qk,
                                                     float* __restrict__ scores) {
    __shared__ float qks[H * D];   // exactly 64 KB
    int t = threadIdx.x;

    // stage qk -> LDS (coalesced float4)
    {
        const float4* src = (const float4*)qk;
        float4* dst = (float4*)qks;
#pragma unroll
        for (int i = 0; i < (H * D / 4) / 256; ++i)   // 16 iters
            dst[t + 256 * i] = src[t + 256 * i];
    }
    __syncthreads();

    int wave = t >> 6;
    int lane = t & 63;
    int row0 = (blockIdx.x * 4 + wave) * 4;           // 4 rows per wave

    // load 4 rows, 16 floats per lane each (coalesced float4)
    const float4* x4 = (const float4*)x;
    float4 xv[4][4];
#pragma unroll
    for (int r = 0; r < 4; ++r) {
        const float4* xr = x4 + (size_t)(row0 + r) * (D / 4);
#pragma unroll
        for (int i = 0; i < 4; ++i)
            xv[r][i] = xr[lane + 64 * i];
    }

    const float4* q4 = (const float4*)qks;
    int b = row0 >> 12;               // rows aligned: whole group in same b
    int n0 = row0 & (N - 1);
    float4* sout = (float4*)(scores + ((size_t)(b * H) << 12) + n0);

#pragma unroll 2
    for (int h = 0; h < H; ++h) {
        float4 qv[4];
#pragma unroll
        for (int i = 0; i < 4; ++i)
            qv[i] = q4[(size_t)h * (D / 4) + lane + 64 * i];

        float p0 = 0.f, p1 = 0.f, p2 = 0.f, p3 = 0.f;
#pragma unroll
        for (int i = 0; i < 4; ++i) {
            p0 += xv[0][i].x * qv[i].x + xv[0][i].y * qv[i].y + xv[0][i].z * qv[i].z + xv[0][i].w * qv[i].w;
            p1 += xv[1][i].x * qv[i].x + xv[1][i].y * qv[i].y + xv[1][i].z * qv[i].z + xv[1][i].w * qv[i].w;
            p2 += xv[2][i].x * qv[i].x + xv[2][i].y * qv[i].y + xv[2][i].z * qv[i].z + xv[2][i].w * qv[i].w;
            p3 += xv[3][i].x * qv[i].x + xv[3][i].y * qv[i].y + xv[3][i].z * qv[i].z + xv[3][i].w * qv[i].w;
        }
#pragma unroll
        for (int off = 32; off > 0; off >>= 1) {
            p0 += __shfl_xor(p0, off, 64);
            p1 += __shfl_xor(p1, off, 64);
            p2 += __shfl_xor(p2, off, 64);
            p3 += __shfl_xor(p3, off, 64);
        }
        if (lane == 0)
            sout[(size_t)h << 10] = make_float4(p0, p1, p2, p3);   // (h*4096)/4 float4s
    }
}

// ---------- softmax over n for each (b,h); one block per (b,h) ----------
__global__ __launch_bounds__(256) void softmax_kernel(float* __restrict__ s) {
    float* p = s + (size_t)blockIdx.x * N;
    int t = threadIdx.x;
    __shared__ float redm[4];
    __shared__ float reds[4];

    float v[16];
    float m = -1e30f;
#pragma unroll
    for (int i = 0; i < 16; ++i) {
        v[i] = p[t + 256 * i];
        m = fmaxf(m, v[i]);
    }
#pragma unroll
    for (int off = 32; off > 0; off >>= 1)
        m = fmaxf(m, __shfl_xor(m, off, 64));
    if ((t & 63) == 0) redm[t >> 6] = m;
    __syncthreads();
    m = fmaxf(fmaxf(redm[0], redm[1]), fmaxf(redm[2], redm[3]));

    float sum = 0.f;
#pragma unroll
    for (int i = 0; i < 16; ++i) {
        v[i] = __expf(v[i] - m);
        sum += v[i];
    }
#pragma unroll
    for (int off = 32; off > 0; off >>= 1)
        sum += __shfl_xor(sum, off, 64);
    if ((t & 63) == 0) reds[t >> 6] = sum;
    __syncthreads();
    sum = reds[0] + reds[1] + reds[2] + reds[3];

    float inv = 1.f / sum;
#pragma unroll
    for (int i = 0; i < 16; ++i) p[t + 256 * i] = v[i] * inv;
}

// ---------- xa[b][h][d] += sum_{n in chunk} A[b][h][n] * x[b][n][d] ----------
#define CHUNK 128
__global__ __launch_bounds__(256) void wsum_kernel(const float* __restrict__ x,
                                                   const float* __restrict__ A,
                                                   float* __restrict__ xa) {
    __shared__ float w[H][CHUNK];
    int c = blockIdx.x;
    int b = blockIdx.y;
    int n0 = c * CHUNK;
    int t = threadIdx.x;

    for (int i = t; i < H * CHUNK; i += 256) {
        int h = i / CHUNK;
        int j = i % CHUNK;
        w[h][j] = A[((size_t)(b * H + h) << 12) + n0 + j];
    }
    __syncthreads();

    float4 acc[H];
#pragma unroll
    for (int h = 0; h < H; ++h) acc[h] = make_float4(0.f, 0.f, 0.f, 0.f);

    const float4* x4 = (const float4*)(x + (size_t)(b * N + n0) * D);
#pragma unroll 2
    for (int r = 0; r < CHUNK; ++r) {
        float4 xv = x4[(size_t)r * (D / 4) + t];
#pragma unroll
        for (int h = 0; h < H; ++h) {
            float wh = w[h][r];
            acc[h].x += wh * xv.x;
            acc[h].y += wh * xv.y;
            acc[h].z += wh * xv.z;
            acc[h].w += wh * xv.w;
        }
    }

    float* xab = xa + (size_t)b * H * D;
#pragma unroll
    for (int h = 0; h < H; ++h) {
        float* dst = xab + h * D + 4 * t;
        atomicAdd(dst + 0, acc[h].x);
        atomicAdd(dst + 1, acc[h].y);
        atomicAdd(dst + 2, acc[h].z);
        atomicAdd(dst + 3, acc[h].w);
    }
}

// ---------- wave-per-output 1024-dot ----------
__device__ __forceinline__ float wave_dot1024(const float* __restrict__ a,
                                              const float* __restrict__ b) {
    const float4* a4 = (const float4*)a;
    const float4* b4 = (const float4*)b;
    int lane = threadIdx.x & 63;
    float acc = 0.f;
#pragma unroll
    for (int i = 0; i < 4; ++i) {
        float4 av = a4[lane + 64 * i];
        float4 bv = b4[lane + 64 * i];
        acc += av.x * bv.x + av.y * bv.y + av.z * bv.z + av.w * bv.w;
    }
#pragma unroll
    for (int off = 32; off > 0; off >>= 1)
        acc += __shfl_xor(acc, off, 64);
    return acc;
}

// ---------- pooled[b][j] = xa[b][j>>6][:] . Wv[j][:] ----------
__global__ __launch_bounds__(256) void pooled_kernel(const float* __restrict__ xa,
                                                     const float* __restrict__ Wv,
                                                     float* __restrict__ pooled) {
    int o = blockIdx.x * 4 + (threadIdx.x >> 6);  // 0..16383
    int b = o >> 10;
    int j = o & (D - 1);
    int h = j >> 6;
    float v = wave_dot1024(xa + (size_t)(b * H + h) * D, Wv + (size_t)j * D);
    if ((threadIdx.x & 63) == 0) pooled[o] = v;
}

// ---------- out[b][j] = pooled[b][:] . Wout[j][:] + bout[j] ----------
__global__ __launch_bounds__(256) void out_kernel(const float* __restrict__ pooled,
                                                  const float* __restrict__ Wout,
                                                  const float* __restrict__ bout,
                                                  float* __restrict__ out) {
    int o = blockIdx.x * 4 + (threadIdx.x >> 6);  // 0..16383
    int b = o >> 10;
    int j = o & (D - 1);
    float v = wave_dot1024(pooled + (size_t)b * D, Wout + (size_t)j * D);
    if ((threadIdx.x & 63) == 0) out[o] = v + bout[j];
}

extern "C" void kernel_launch(void* const* d_in, const int* in_sizes, int n_in,
                              void* d_out, int out_size, void* d_ws, size_t ws_size,
                              hipStream_t stream) {
    const float* x     = (const float*)d_in[0];
    const float* Wk    = (const float*)d_in[1];
    const float* Wv    = (const float*)d_in[2];
    const float* query = (const float*)d_in[3];
    const float* Wout  = (const float*)d_in[4];
    const float* bout  = (const float*)d_in[5];
    float* out = (float*)d_out;

    float* qk     = (float*)d_ws;                    // 16384
    float* scores = qk + H * D;                      // 1048576
    float* xa     = scores + (size_t)B * H * N;      // 262144
    float* pooled = xa + (size_t)B * H * D;          // 16384

    qk_kernel<<<64, 256, 0, stream>>>(query, Wk, qk);
    zero_kernel<<<(B * H * D / 4 + 255) / 256, 256, 0, stream>>>(xa, B * H * D / 4);

    // scores: one pass over x (wave-per-4-rows, qk in LDS)
    scores_kernel<<<(B * N) / 16, 256, 0, stream>>>(x, qk, scores);

    // softmax per (b,h)
    softmax_kernel<<<B * H, 256, 0, stream>>>(scores);

    // weighted sum: second pass over x
    wsum_kernel<<<dim3(N / CHUNK, B), 256, 0, stream>>>(x, scores, xa);

    // small tail GEMVs
    pooled_kernel<<<(B * D) / 4, 256, 0, stream>>>(xa, Wv, pooled);
    out_kernel<<<(B * D) / 4, 256, 0, stream>>>(pooled, Wout, bout, out);
}

// Round 3
// 468.742 us; speedup vs baseline: 2.1405x; 1.1948x over previous
//
#include <hip/hip_runtime.h>
#include <math.h>

#define H 16
#define D 1024
#define DK 64
#define B 16
#define N 4096
#define SCALE_INV 0.125f

// ws layout (floats):
//   qk     [H][D]          16384
//   scores [B][H][N]       1048576  (in-place softmax -> A)
//   xa     [B][H][D]       262144
//   pooled [B][D]          16384
//   P      [NC][B][H][D]   16777216  (wsum partials, NC=64)
// total ~72.5 MB

#define NC 64            // n-chunks for wsum stage 1
#define CHUNK (N / NC)   // 64 rows per chunk

// ---------- qk[h][d] = (1/8) * sum_dk query[h*64+dk] * Wk[(h*64+dk)*D + d] ----------
__global__ __launch_bounds__(256) void qk_kernel(const float* __restrict__ query,
                                                 const float* __restrict__ Wk,
                                                 float* __restrict__ qk) {
    int t = blockIdx.x * 256 + threadIdx.x;   // 0..16383
    int h = t >> 10;
    int d = t & (D - 1);
    float acc = 0.f;
#pragma unroll 8
    for (int dk = 0; dk < DK; ++dk)
        acc += query[h * DK + dk] * Wk[(size_t)(h * DK + dk) * D + d];
    qk[t] = acc * SCALE_INV;
}

// ---------- scores[b][h][n] = x_row . qk[h] ----------
// One wave handles 4 rows. qk staged in LDS in two 8-head passes (32 KB).
// Block = 256 threads = 4 waves = 16 rows. Grid = 65536/16 = 4096 blocks.
__global__ __launch_bounds__(256) void scores_kernel(const float* __restrict__ x,
                                                     const float* __restrict__ qk,
                                                     float* __restrict__ scores) {
    __shared__ float qks[8 * D];   // 32 KB: 8 heads per pass
    int t = threadIdx.x;
    int wave = t >> 6;
    int lane = t & 63;
    int row0 = (blockIdx.x * 4 + wave) * 4;           // 4 rows per wave

    // load 4 rows, 16 floats per lane each (coalesced float4)
    const float4* x4 = (const float4*)x;
    float4 xv[4][4];
#pragma unroll
    for (int r = 0; r < 4; ++r) {
        const float4* xr = x4 + (size_t)(row0 + r) * (D / 4);
#pragma unroll
        for (int i = 0; i < 4; ++i)
            xv[r][i] = xr[lane + 64 * i];
    }

    int b = row0 >> 12;               // N = 4096
    int n0 = row0 & (N - 1);
    float4* sout = (float4*)(scores + ((size_t)(b * H) << 12) + n0);
    const float4* q4 = (const float4*)qks;

    for (int pass = 0; pass < 2; ++pass) {
        if (pass) __syncthreads();     // wait for pass-0 readers before restaging
        {   // stage 8 heads -> LDS (coalesced float4)
            const float4* src = (const float4*)(qk + pass * 8 * D);
            float4* dst = (float4*)qks;
#pragma unroll
            for (int i = 0; i < (8 * D / 4) / 256; ++i)   // 8 iters
                dst[t + 256 * i] = src[t + 256 * i];
        }
        __syncthreads();

#pragma unroll 2
        for (int h8 = 0; h8 < 8; ++h8) {
            float4 qv[4];
#pragma unroll
            for (int i = 0; i < 4; ++i)
                qv[i] = q4[(size_t)h8 * (D / 4) + lane + 64 * i];

            float p0 = 0.f, p1 = 0.f, p2 = 0.f, p3 = 0.f;
#pragma unroll
            for (int i = 0; i < 4; ++i) {
                p0 += xv[0][i].x * qv[i].x + xv[0][i].y * qv[i].y + xv[0][i].z * qv[i].z + xv[0][i].w * qv[i].w;
                p1 += xv[1][i].x * qv[i].x + xv[1][i].y * qv[i].y + xv[1][i].z * qv[i].z + xv[1][i].w * qv[i].w;
                p2 += xv[2][i].x * qv[i].x + xv[2][i].y * qv[i].y + xv[2][i].z * qv[i].z + xv[2][i].w * qv[i].w;
                p3 += xv[3][i].x * qv[i].x + xv[3][i].y * qv[i].y + xv[3][i].z * qv[i].z + xv[3][i].w * qv[i].w;
            }
#pragma unroll
            for (int off = 32; off > 0; off >>= 1) {
                p0 += __shfl_xor(p0, off, 64);
                p1 += __shfl_xor(p1, off, 64);
                p2 += __shfl_xor(p2, off, 64);
                p3 += __shfl_xor(p3, off, 64);
            }
            if (lane == 0) {
                int h = pass * 8 + h8;
                sout[(size_t)h << 10] = make_float4(p0, p1, p2, p3);
            }
        }
    }
}

// ---------- softmax over n for each (b,h); one block per (b,h) ----------
__global__ __launch_bounds__(256) void softmax_kernel(float* __restrict__ s) {
    float* p = s + (size_t)blockIdx.x * N;
    int t = threadIdx.x;
    __shared__ float redm[4];
    __shared__ float reds[4];

    float v[16];
    float m = -1e30f;
#pragma unroll
    for (int i = 0; i < 16; ++i) {
        v[i] = p[t + 256 * i];
        m = fmaxf(m, v[i]);
    }
#pragma unroll
    for (int off = 32; off > 0; off >>= 1)
        m = fmaxf(m, __shfl_xor(m, off, 64));
    if ((t & 63) == 0) redm[t >> 6] = m;
    __syncthreads();
    m = fmaxf(fmaxf(redm[0], redm[1]), fmaxf(redm[2], redm[3]));

    float sum = 0.f;
#pragma unroll
    for (int i = 0; i < 16; ++i) {
        v[i] = __expf(v[i] - m);
        sum += v[i];
    }
#pragma unroll
    for (int off = 32; off > 0; off >>= 1)
        sum += __shfl_xor(sum, off, 64);
    if ((t & 63) == 0) reds[t >> 6] = sum;
    __syncthreads();
    sum = reds[0] + reds[1] + reds[2] + reds[3];

    float inv = 1.f / sum;
#pragma unroll
    for (int i = 0; i < 16; ++i) p[t + 256 * i] = v[i] * inv;
}

// ---------- stage 1: P[c][b][h][d] = sum_{n in chunk c} A[b][h][n] * x[b][n][d] ----------
// grid = (NC, B); block = 256 threads, thread t owns d = 4t..4t+3. No atomics.
__global__ __launch_bounds__(256) void wsum_partial_kernel(const float* __restrict__ x,
                                                           const float* __restrict__ A,
                                                           float* __restrict__ P) {
    __shared__ float w[H][CHUNK];   // 4 KB
    int c = blockIdx.x;
    int b = blockIdx.y;
    int n0 = c * CHUNK;
    int t = threadIdx.x;

    // stage A -> LDS: 16 heads x 64 rows = 1024 floats; thread t loads one float4
    {
        int h = t >> 4;           // 0..15
        int j4 = (t & 15) * 4;    // 0..60
        const float4 a = *(const float4*)(A + ((size_t)(b * H + h) << 12) + n0 + j4);
        *(float4*)&w[h][j4] = a;
    }
    __syncthreads();

    float4 acc[H];
#pragma unroll
    for (int h = 0; h < H; ++h) acc[h] = make_float4(0.f, 0.f, 0.f, 0.f);

    const float4* xb = (const float4*)(x + (size_t)(b * N + n0) * D);

    // 4-row register prefetch
    float4 cur[4];
#pragma unroll
    for (int i = 0; i < 4; ++i) cur[i] = xb[(size_t)i * (D / 4) + t];

    for (int r0 = 0; r0 < CHUNK; r0 += 4) {
        float4 nxt[4];
        if (r0 + 4 < CHUNK) {
#pragma unroll
            for (int i = 0; i < 4; ++i)
                nxt[i] = xb[(size_t)(r0 + 4 + i) * (D / 4) + t];
        }
#pragma unroll
        for (int h = 0; h < H; ++h) {
            float4 wv = *(const float4*)&w[h][r0];   // broadcast ds_read_b128
            acc[h].x += wv.x * cur[0].x + wv.y * cur[1].x + wv.z * cur[2].x + wv.w * cur[3].x;
            acc[h].y += wv.x * cur[0].y + wv.y * cur[1].y + wv.z * cur[2].y + wv.w * cur[3].y;
            acc[h].z += wv.x * cur[0].z + wv.y * cur[1].z + wv.z * cur[2].z + wv.w * cur[3].z;
            acc[h].w += wv.x * cur[0].w + wv.y * cur[1].w + wv.z * cur[2].w + wv.w * cur[3].w;
        }
#pragma unroll
        for (int i = 0; i < 4; ++i) cur[i] = nxt[i];
    }

    // coalesced float4 stores: P block (c,b) is 16K floats contiguous
    float4* Pout = (float4*)(P + ((size_t)(c * B + b) * H) * D);
#pragma unroll
    for (int h = 0; h < H; ++h)
        Pout[(size_t)h * (D / 4) + t] = acc[h];
}

// ---------- stage 2: xa[b][h][d] = sum_c P[c][b][h][d] ----------
// grid = B*H blocks; thread t owns one float4 of xa[b][h].
__global__ __launch_bounds__(256) void wsum_reduce_kernel(const float* __restrict__ P,
                                                          float* __restrict__ xa) {
    int bh = blockIdx.x;          // 0..255 = b*H+h
    int t = threadIdx.x;
    const float4* P4 = (const float4*)P;
    float4 acc = make_float4(0.f, 0.f, 0.f, 0.f);
#pragma unroll 8
    for (int c = 0; c < NC; ++c) {
        float4 v = P4[((size_t)c * B * H + bh) * (D / 4) + t];
        acc.x += v.x; acc.y += v.y; acc.z += v.z; acc.w += v.w;
    }
    ((float4*)xa)[(size_t)bh * (D / 4) + t] = acc;
}

// ---------- wave-per-output 1024-dot ----------
__device__ __forceinline__ float wave_dot1024(const float* __restrict__ a,
                                              const float* __restrict__ b) {
    const float4* a4 = (const float4*)a;
    const float4* b4 = (const float4*)b;
    int lane = threadIdx.x & 63;
    float acc = 0.f;
#pragma unroll
    for (int i = 0; i < 4; ++i) {
        float4 av = a4[lane + 64 * i];
        float4 bv = b4[lane + 64 * i];
        acc += av.x * bv.x + av.y * bv.y + av.z * bv.z + av.w * bv.w;
    }
#pragma unroll
    for (int off = 32; off > 0; off >>= 1)
        acc += __shfl_xor(acc, off, 64);
    return acc;
}

// ---------- pooled[b][j] = xa[b][j>>6][:] . Wv[j][:] ----------
__global__ __launch_bounds__(256) void pooled_kernel(const float* __restrict__ xa,
                                                     const float* __restrict__ Wv,
                                                     float* __restrict__ pooled) {
    int o = blockIdx.x * 4 + (threadIdx.x >> 6);  // 0..16383
    int b = o >> 10;
    int j = o & (D - 1);
    int h = j >> 6;
    float v = wave_dot1024(xa + (size_t)(b * H + h) * D, Wv + (size_t)j * D);
    if ((threadIdx.x & 63) == 0) pooled[o] = v;
}

// ---------- out[b][j] = pooled[b][:] . Wout[j][:] + bout[j] ----------
__global__ __launch_bounds__(256) void out_kernel(const float* __restrict__ pooled,
                                                  const float* __restrict__ Wout,
                                                  const float* __restrict__ bout,
                                                  float* __restrict__ out) {
    int o = blockIdx.x * 4 + (threadIdx.x >> 6);  // 0..16383
    int b = o >> 10;
    int j = o & (D - 1);
    float v = wave_dot1024(pooled + (size_t)b * D, Wout + (size_t)j * D);
    if ((threadIdx.x & 63) == 0) out[o] = v + bout[j];
}

extern "C" void kernel_launch(void* const* d_in, const int* in_sizes, int n_in,
                              void* d_out, int out_size, void* d_ws, size_t ws_size,
                              hipStream_t stream) {
    const float* x     = (const float*)d_in[0];
    const float* Wk    = (const float*)d_in[1];
    const float* Wv    = (const float*)d_in[2];
    const float* query = (const float*)d_in[3];
    const float* Wout  = (const float*)d_in[4];
    const float* bout  = (const float*)d_in[5];
    float* out = (float*)d_out;

    float* qk     = (float*)d_ws;                    // 16384
    float* scores = qk + H * D;                      // 1048576
    float* xa     = scores + (size_t)B * H * N;      // 262144
    float* pooled = xa + (size_t)B * H * D;          // 16384
    float* P      = pooled + (size_t)B * D;          // 16777216

    qk_kernel<<<64, 256, 0, stream>>>(query, Wk, qk);

    // scores: one pass over x (wave-per-4-rows, qk in LDS two-pass)
    scores_kernel<<<(B * N) / 16, 256, 0, stream>>>(x, qk, scores);

    // softmax per (b,h)
    softmax_kernel<<<B * H, 256, 0, stream>>>(scores);

    // weighted sum: second pass over x, two-stage (no atomics)
    wsum_partial_kernel<<<dim3(NC, B), 256, 0, stream>>>(x, scores, P);
    wsum_reduce_kernel<<<B * H, 256, 0, stream>>>(P, xa);

    // small tail GEMVs
    pooled_kernel<<<(B * D) / 4, 256, 0, stream>>>(xa, Wv, pooled);
    out_kernel<<<(B * D) / 4, 256, 0, stream>>>(pooled, Wout, bout, out);
}